// Round 14
// baseline (220.184 us; speedup 1.0000x reference)
//
#include <hip/hip_runtime.h>
#include <hip/hip_bf16.h>
#include <math.h>

typedef __bf16 bf16_t;
typedef __attribute__((ext_vector_type(8))) __bf16 bf16x8;
typedef __attribute__((ext_vector_type(4))) __bf16 bf16x4;
typedef __attribute__((ext_vector_type(4))) float f32x4;

#define MFMA_16x16x32(A_, B_, C_) __builtin_amdgcn_mfma_f32_16x16x32_bf16((A_), (B_), (C_), 0, 0, 0)

#define Bsz 4
#define Ssz 2048
#define Dsz 1024
#define Hh 16
#define DKd 64
#define Mrows (Bsz * Ssz)  /* 8192 */
#define N1 (3 * Dsz)       /* 3072 */
#define KD Dsz             /* 1024 */

// raw v_exp_f32 (1 instr; libm exp2f adds denorm-guard selects)
static __device__ __forceinline__ float fast_exp2(float x) {
  float r;
  asm("v_exp_f32 %0, %1" : "=v"(r) : "v"(x));
  return r;
}

// ---- fused prep: x/wqkv/wo f32->bf16 converts + RoPE table, one launch ----
__global__ void prep_kernel(const float* __restrict__ x, const float* __restrict__ wqkv,
                            const float* __restrict__ wo, const int* __restrict__ pos,
                            bf16_t* __restrict__ xb, bf16_t* __restrict__ wqkvb,
                            bf16_t* __restrict__ wob, float2* __restrict__ tab) {
  constexpr int N4X = Mrows * KD / 4;
  constexpr int N4W = N1 * KD / 4;
  constexpr int N4O = Dsz * KD / 4;
  constexpr int NRT = Ssz * 32;
  const int i = blockIdx.x * blockDim.x + threadIdx.x;
  if (i < N4X) {
    float4 v = reinterpret_cast<const float4*>(x)[i];
    bf16x4 o = {(bf16_t)v.x, (bf16_t)v.y, (bf16_t)v.z, (bf16_t)v.w};
    reinterpret_cast<bf16x4*>(xb)[i] = o;
  } else if (i < N4X + N4W) {
    const int j = i - N4X;
    float4 v = reinterpret_cast<const float4*>(wqkv)[j];
    bf16x4 o = {(bf16_t)v.x, (bf16_t)v.y, (bf16_t)v.z, (bf16_t)v.w};
    reinterpret_cast<bf16x4*>(wqkvb)[j] = o;
  } else if (i < N4X + N4W + N4O) {
    const int j = i - N4X - N4W;
    float4 v = reinterpret_cast<const float4*>(wo)[j];
    bf16x4 o = {(bf16_t)v.x, (bf16_t)v.y, (bf16_t)v.z, (bf16_t)v.w};
    reinterpret_cast<bf16x4*>(wob)[j] = o;
  } else if (i < N4X + N4W + N4O + NRT) {
    const int j = i - N4X - N4W - N4O;
    const int s = j >> 5, f = j & 31;
    float inv_freq = powf(10000.0f, -(float)(2 * f) / 64.0f);
    float a = (float)pos[s] * inv_freq;
    tab[j] = make_float2(cosf(a), sinf(a));
  }
}

// ============ QKV GEMM: 256(M) x 192(N), BK=64, 8 waves, 8-PHASE (R10) ======
__global__ __launch_bounds__(512, 1) void gemm256_qkv_kernel(
    const bf16_t* __restrict__ A, const bf16_t* __restrict__ Bt,
    bf16_t* __restrict__ qb, bf16_t* __restrict__ kb, bf16_t* __restrict__ vtb,
    const float2* __restrict__ tab) {
  constexpr int NT = KD / 64;  // 16
  __shared__ __align__(16) bf16_t As[2][256 * 64];
  __shared__ __align__(16) bf16_t Bs[2][192 * 64];
  const int t = threadIdx.x;
  const int w = t >> 6, l = t & 63;
  const int lr = l & 15, lk = l >> 4;
  const int rs = lr >> 1;             // read-side swizzle (0..7)
  const int wm = w >> 2, wn = w & 3;  // 2M x 4N waves
  const int m0 = blockIdx.y * 256, n0 = blockIdx.x * 192;

  const int gcol = ((t & 7) ^ ((t >> 4) & 7)) * 8;
  const bf16_t* gA = A + (size_t)(m0 + (t >> 3)) * KD + gcol;
  const bf16_t* gB = Bt + (size_t)(n0 + (t >> 3)) * KD + gcol;

  f32x4 acc[8][3] = {};
  bf16x8 bfv[3][2];

#define LDA_(I_, SB_, KT_)                                                        \
  __builtin_amdgcn_global_load_lds(gA + (size_t)(I_) * 64 * KD + (KT_),           \
                                   &As[SB_][((I_) * 64 + w * 8) * 64], 16, 0, 0)
#define LDB_(I_, SB_, KT_)                                                        \
  __builtin_amdgcn_global_load_lds(gB + (size_t)(I_) * 64 * KD + (KT_),           \
                                   &Bs[SB_][((I_) * 64 + w * 8) * 64], 16, 0, 0)

#define PH(BUF_, P_, STG0_, STG1_, VMW_)                                          \
  do {                                                                            \
    if ((P_) == 0) {                                                              \
      _Pragma("unroll") for (int n_ = 0; n_ < 3; ++n_) {                          \
        const int R_ = wn * 48 + n_ * 16 + lr;                                    \
        bfv[n_][0] = *reinterpret_cast<const bf16x8*>(                            \
            &Bs[BUF_][R_ * 64 + ((lk ^ rs) * 8)]);                                \
        bfv[n_][1] = *reinterpret_cast<const bf16x8*>(                            \
            &Bs[BUF_][R_ * 64 + (((4 + lk) ^ rs) * 8)]);                          \
      }                                                                           \
    }                                                                             \
    bf16x8 af0_[2], af1_[2];                                                      \
    {                                                                             \
      const int Ra_ = wm * 128 + (P_) * 32 + lr;                                  \
      const int Rb_ = Ra_ + 16;                                                   \
      af0_[0] = *reinterpret_cast<const bf16x8*>(&As[BUF_][Ra_ * 64 + ((lk ^ rs) * 8)]);       \
      af0_[1] = *reinterpret_cast<const bf16x8*>(&As[BUF_][Ra_ * 64 + (((4 + lk) ^ rs) * 8)]); \
      af1_[0] = *reinterpret_cast<const bf16x8*>(&As[BUF_][Rb_ * 64 + ((lk ^ rs) * 8)]);       \
      af1_[1] = *reinterpret_cast<const bf16x8*>(&As[BUF_][Rb_ * 64 + (((4 + lk) ^ rs) * 8)]); \
    }                                                                             \
    STG0_;                                                                        \
    STG1_;                                                                        \
    __builtin_amdgcn_s_barrier();                                                 \
    asm volatile("s_waitcnt lgkmcnt(0)" ::: "memory");                            \
    __builtin_amdgcn_sched_barrier(0);                                            \
    __builtin_amdgcn_s_setprio(1);                                                \
    _Pragma("unroll") for (int n_ = 0; n_ < 3; ++n_) {                            \
      acc[(P_)*2][n_] = MFMA_16x16x32(af0_[0], bfv[n_][0], acc[(P_)*2][n_]);      \
      acc[(P_)*2][n_] = MFMA_16x16x32(af0_[1], bfv[n_][1], acc[(P_)*2][n_]);      \
      acc[(P_)*2 + 1][n_] = MFMA_16x16x32(af1_[0], bfv[n_][0], acc[(P_)*2 + 1][n_]); \
      acc[(P_)*2 + 1][n_] = MFMA_16x16x32(af1_[1], bfv[n_][1], acc[(P_)*2 + 1][n_]); \
    }                                                                             \
    __builtin_amdgcn_s_setprio(0);                                                \
    VMW_;                                                                         \
    __builtin_amdgcn_s_barrier();                                                 \
  } while (0)

#define VM4_ do { asm volatile("s_waitcnt vmcnt(4)" ::: "memory"); __builtin_amdgcn_sched_barrier(0); } while (0)
#define VM2_ do { asm volatile("s_waitcnt vmcnt(2)" ::: "memory"); __builtin_amdgcn_sched_barrier(0); } while (0)

#define TILE_(BUF_, KTN_)                                                         \
  do {                                                                            \
    PH(BUF_, 0, LDB_(0, (BUF_) ^ 1, KTN_), LDB_(1, (BUF_) ^ 1, KTN_), (void)0);   \
    PH(BUF_, 1, LDB_(2, (BUF_) ^ 1, KTN_), LDA_(0, (BUF_) ^ 1, KTN_), VM4_);      \
    PH(BUF_, 2, LDA_(2, (BUF_) ^ 1, KTN_), LDA_(1, (BUF_) ^ 1, KTN_), (void)0);   \
    PH(BUF_, 3, LDA_(3, (BUF_) ^ 1, KTN_), (void)0, VM2_);                        \
  } while (0)

  LDB_(0, 0, 0); LDB_(1, 0, 0); LDB_(2, 0, 0);
  LDA_(0, 0, 0); LDA_(2, 0, 0); LDA_(1, 0, 0); LDA_(3, 0, 0);
  asm volatile("s_waitcnt vmcnt(2)" ::: "memory");
  __builtin_amdgcn_s_barrier();

#pragma unroll 1
  for (int tt = 0; tt < NT; tt += 2) {
    const int ktn0 = ((tt + 1) & (NT - 1)) * 64;  // last tile wraps to 0 (dead buf)
    TILE_(0, ktn0);
    const int ktn1 = ((tt + 2) & (NT - 1)) * 64;
    TILE_(1, ktn1);
  }
#undef TILE_
#undef VM4_
#undef VM2_
#undef PH
#undef LDA_
#undef LDB_

  // ---- epilogue: per-n section decode ----
#pragma unroll
  for (int n = 0; n < 3; ++n) {
    const int colbase = n0 + wn * 48 + n * 16;
    const int sect = colbase >> 10;  // 0=q 1=k 2=v
    const int h = (colbase >> 6) & 15;
    const int dk = (colbase & 63) + lr;
    if (sect < 2) {
      bf16_t* dst0 = (sect == 0) ? qb : kb;
#pragma unroll
      for (int m = 0; m < 8; ++m)
#pragma unroll
        for (int r = 0; r < 4; ++r) {
          const int grow = m0 + wm * 128 + m * 16 + lk * 4 + r;
          const int bb = grow >> 11, s = grow & (Ssz - 1);
          const float v = acc[m][n][r];
          const float pv = __shfl_xor(v, 1);
          const float2 cs = tab[(s << 5) | (dk >> 1)];
          float vr = (dk & 1) ? (pv * cs.y + v * cs.x) : (v * cs.x - pv * cs.y);
          if (sect == 0) vr *= 0.18033688f;  // (1/8) * log2(e): exp2 softmax
          dst0[((size_t)(bb * Hh + h) * Ssz + s) * DKd + dk] = (bf16_t)vr;
        }
    } else {
#pragma unroll
      for (int m = 0; m < 8; ++m) {
        const int grow0 = m0 + wm * 128 + m * 16 + lk * 4;
        const int bb = grow0 >> 11, s0 = grow0 & (Ssz - 1);
        const bf16x4 ov = {(bf16_t)acc[m][n][0], (bf16_t)acc[m][n][1],
                           (bf16_t)acc[m][n][2], (bf16_t)acc[m][n][3]};
        *reinterpret_cast<bf16x4*>(
            vtb + ((size_t)(bb * Hh + h) * DKd + dk) * Ssz + s0) = ov;
      }
    }
  }
}

// ============ out-proj GEMM: 256(M) x 128(N), BK=64, 8 waves, 8-PHASE =======
__global__ __launch_bounds__(512, 1) void gemm_out_kernel(
    const bf16_t* __restrict__ A, const bf16_t* __restrict__ Bt,
    float* __restrict__ fout) {
  constexpr int NT = KD / 64;  // 16
  __shared__ __align__(16) bf16_t As[2][256 * 64];
  __shared__ __align__(16) bf16_t Bs[2][128 * 64];
  const int t = threadIdx.x;
  const int w = t >> 6, l = t & 63;
  const int lr = l & 15, lk = l >> 4;
  const int rs = lr >> 1;
  const int wm = w >> 2, wn = w & 3;
  const int m0 = blockIdx.y * 256, n0 = blockIdx.x * 128;

  const int gcol = ((t & 7) ^ ((t >> 4) & 7)) * 8;
  const bf16_t* gA = A + (size_t)(m0 + (t >> 3)) * KD + gcol;
  const bf16_t* gB = Bt + (size_t)(n0 + (t >> 3)) * KD + gcol;

  f32x4 acc[8][2] = {};
  bf16x8 bfv[2][2];

#define OLDA_(I_, SB_, KT_)                                                       \
  __builtin_amdgcn_global_load_lds(gA + (size_t)(I_) * 64 * KD + (KT_),           \
                                   &As[SB_][((I_) * 64 + w * 8) * 64], 16, 0, 0)
#define OLDB_(I_, SB_, KT_)                                                       \
  __builtin_amdgcn_global_load_lds(gB + (size_t)(I_) * 64 * KD + (KT_),           \
                                   &Bs[SB_][((I_) * 64 + w * 8) * 64], 16, 0, 0)

#define OPH(BUF_, P_, STG0_, STG1_, VMW_)                                         \
  do {                                                                            \
    if ((P_) == 0) {                                                              \
      _Pragma("unroll") for (int n_ = 0; n_ < 2; ++n_) {                          \
        const int R_ = wn * 32 + n_ * 16 + lr;                                    \
        bfv[n_][0] = *reinterpret_cast<const bf16x8*>(                            \
            &Bs[BUF_][R_ * 64 + ((lk ^ rs) * 8)]);                                \
        bfv[n_][1] = *reinterpret_cast<const bf16x8*>(                            \
            &Bs[BUF_][R_ * 64 + (((4 + lk) ^ rs) * 8)]);                          \
      }                                                                           \
    }                                                                             \
    bf16x8 af0_[2], af1_[2];                                                      \
    {                                                                             \
      const int Ra_ = wm * 128 + (P_) * 32 + lr;                                  \
      const int Rb_ = Ra_ + 16;                                                   \
      af0_[0] = *reinterpret_cast<const bf16x8*>(&As[BUF_][Ra_ * 64 + ((lk ^ rs) * 8)]);       \
      af0_[1] = *reinterpret_cast<const bf16x8*>(&As[BUF_][Ra_ * 64 + (((4 + lk) ^ rs) * 8)]); \
      af1_[0] = *reinterpret_cast<const bf16x8*>(&As[BUF_][Rb_ * 64 + ((lk ^ rs) * 8)]);       \
      af1_[1] = *reinterpret_cast<const bf16x8*>(&As[BUF_][Rb_ * 64 + (((4 + lk) ^ rs) * 8)]); \
    }                                                                             \
    STG0_;                                                                        \
    STG1_;                                                                        \
    __builtin_amdgcn_s_barrier();                                                 \
    asm volatile("s_waitcnt lgkmcnt(0)" ::: "memory");                            \
    __builtin_amdgcn_sched_barrier(0);                                            \
    __builtin_amdgcn_s_setprio(1);                                                \
    _Pragma("unroll") for (int n_ = 0; n_ < 2; ++n_) {                            \
      acc[(P_)*2][n_] = MFMA_16x16x32(af0_[0], bfv[n_][0], acc[(P_)*2][n_]);      \
      acc[(P_)*2][n_] = MFMA_16x16x32(af0_[1], bfv[n_][1], acc[(P_)*2][n_]);      \
      acc[(P_)*2 + 1][n_] = MFMA_16x16x32(af1_[0], bfv[n_][0], acc[(P_)*2 + 1][n_]); \
      acc[(P_)*2 + 1][n_] = MFMA_16x16x32(af1_[1], bfv[n_][1], acc[(P_)*2 + 1][n_]); \
    }                                                                             \
    __builtin_amdgcn_s_setprio(0);                                                \
    VMW_;                                                                         \
    __builtin_amdgcn_s_barrier();                                                 \
  } while (0)

#define OVM4_ do { asm volatile("s_waitcnt vmcnt(4)" ::: "memory"); __builtin_amdgcn_sched_barrier(0); } while (0)
#define OVM2_ do { asm volatile("s_waitcnt vmcnt(2)" ::: "memory"); __builtin_amdgcn_sched_barrier(0); } while (0)

#define OTILE_(BUF_, KTN_)                                                        \
  do {                                                                            \
    OPH(BUF_, 0, OLDB_(0, (BUF_) ^ 1, KTN_), OLDB_(1, (BUF_) ^ 1, KTN_), (void)0);\
    OPH(BUF_, 1, OLDA_(0, (BUF_) ^ 1, KTN_), OLDA_(2, (BUF_) ^ 1, KTN_), OVM4_);  \
    OPH(BUF_, 2, OLDA_(1, (BUF_) ^ 1, KTN_), OLDA_(3, (BUF_) ^ 1, KTN_), (void)0);\
    OPH(BUF_, 3, (void)0, (void)0, OVM2_);                                        \
  } while (0)

  OLDB_(0, 0, 0); OLDB_(1, 0, 0);
  OLDA_(0, 0, 0); OLDA_(2, 0, 0); OLDA_(1, 0, 0); OLDA_(3, 0, 0);
  asm volatile("s_waitcnt vmcnt(2)" ::: "memory");
  __builtin_amdgcn_s_barrier();

#pragma unroll 1
  for (int tt = 0; tt < NT; tt += 2) {
    const int ktn0 = ((tt + 1) & (NT - 1)) * 64;
    OTILE_(0, ktn0);
    const int ktn1 = ((tt + 2) & (NT - 1)) * 64;
    OTILE_(1, ktn1);
  }
#undef OTILE_
#undef OVM4_
#undef OVM2_
#undef OPH
#undef OLDA_
#undef OLDB_

#pragma unroll
  for (int m = 0; m < 8; ++m)
#pragma unroll
    for (int r = 0; r < 4; ++r) {
      const int grow = m0 + wm * 128 + m * 16 + lk * 4 + r;
      float* op = fout + (size_t)grow * Dsz + n0 + wn * 32 + lr;
      op[0] = acc[m][0][r];
      op[16] = acc[m][1][r];
    }
}

// ---------------- causal flash attention ----------------
// KV staged in PAIRS of 64-tiles (ring 2 slots x 2 chunks, 64 KB): one barrier
// per 128 kv -> waves drift a full tile, anti-aligning MFMA/VALU phases.
// Row-sum via MFMA ones-trick: lacc = mfma(ones, pb, lacc) -- the MFMA's
// internal k-reduction crosses lanes, so lacc[0] IS the denominator (no adds,
// no epilogue shuffle). exp2 softmax (raw v_exp) + defer-max (T13).
__global__ __launch_bounds__(256, 3) void attn_kernel(
    const bf16_t* __restrict__ qb, const bf16_t* __restrict__ kb,
    const bf16_t* __restrict__ vtb, bf16_t* __restrict__ aout) {
  __shared__ __align__(16) bf16_t Ks[2][2][64 * 64];
  __shared__ __align__(16) bf16_t Vs[2][2][64 * 64];
  const int t = threadIdx.x, w = t >> 6, l = t & 63;
  const int lr = l & 15, lk = l >> 4;
  const int bid = blockIdx.x;
  const int bh = (bid & 7) * 8 + ((bid >> 3) & 7);
  const int qt = 15 - (bid >> 6);  // heavy-first
  const int q0 = qt * 128;
  const int sub0 = q0 + w * 32;
  const int npairs = qt + 1;

  const bf16_t* qbase = qb + ((size_t)bh * Ssz + sub0) * DKd;
  bf16x8 qf[2][2];
#pragma unroll
  for (int s = 0; s < 2; ++s) {
    qf[s][0] = *reinterpret_cast<const bf16x8*>(qbase + (s * 16 + lr) * DKd + lk * 8);
    qf[s][1] = *reinterpret_cast<const bf16x8*>(qbase + (s * 16 + lr) * DKd + 32 + lk * 8);
  }
  bf16x8 ones;
#pragma unroll
  for (int i = 0; i < 8; ++i) ones[i] = (bf16_t)1.0f;

  f32x4 o[2][4] = {};
  f32x4 lacc[2] = {};
  float mrow[2] = {-INFINITY, -INFINITY};

  const int srow = t >> 2;
  const int scc = (t & 3) * 2;
  const bf16_t* kg = kb + ((size_t)bh * Ssz + srow) * DKd + scc * 8;
  const bf16_t* vg = vtb + ((size_t)bh * DKd + srow) * Ssz + scc * 8;
  const int koff0 = srow * 64 + ((scc ^ (srow & 7)) * 8);
  const int koff1 = srow * 64 + (((scc + 1) ^ (srow & 7)) * 8);
  int voff[4];
#pragma unroll
  for (int u = 0; u < 2; ++u) {
    const int c = scc + u;
    const int B = 32 * (c >> 2) + 16 * (c & 1) + 4 * ((c & 3) >> 1);
    const int ch = B >> 3, off = B & 7;
    voff[2 * u] = srow * 64 + ((ch ^ (srow & 7)) * 8) + off;
    voff[2 * u + 1] = srow * 64 + (((ch + 1) ^ (srow & 7)) * 8) + off;
  }

  const int fx0 = (lk ^ (lr & 7)) * 8;
  const int fx1 = ((lk + 4) ^ (lr & 7)) * 8;
  const int frow = lr * 64;

  bf16x8 pk[2][2], pv[2][2];  // [chunk][half]

#define LOAD_PAIR_(P_)                                                            \
  do {                                                                            \
    _Pragma("unroll") for (int c_ = 0; c_ < 2; ++c_) {                            \
      const size_t kvo_ = (size_t)((P_) * 128 + c_ * 64);                         \
      pk[c_][0] = *reinterpret_cast<const bf16x8*>(kg + kvo_ * DKd);              \
      pk[c_][1] = *reinterpret_cast<const bf16x8*>(kg + kvo_ * DKd + 8);          \
      pv[c_][0] = *reinterpret_cast<const bf16x8*>(vg + kvo_);                    \
      pv[c_][1] = *reinterpret_cast<const bf16x8*>(vg + kvo_ + 8);                \
    }                                                                             \
  } while (0)

#define WRITE_PAIR_(SL_)                                                          \
  do {                                                                            \
    _Pragma("unroll") for (int c_ = 0; c_ < 2; ++c_) {                            \
      *reinterpret_cast<bf16x8*>(&Ks[SL_][c_][koff0]) = pk[c_][0];                \
      *reinterpret_cast<bf16x8*>(&Ks[SL_][c_][koff1]) = pk[c_][1];                \
      *reinterpret_cast<bf16x4*>(&Vs[SL_][c_][voff[0]]) =                         \
          __builtin_shufflevector(pv[c_][0], pv[c_][0], 0, 1, 2, 3);              \
      *reinterpret_cast<bf16x4*>(&Vs[SL_][c_][voff[1]]) =                         \
          __builtin_shufflevector(pv[c_][0], pv[c_][0], 4, 5, 6, 7);              \
      *reinterpret_cast<bf16x4*>(&Vs[SL_][c_][voff[2]]) =                         \
          __builtin_shufflevector(pv[c_][1], pv[c_][1], 0, 1, 2, 3);              \
      *reinterpret_cast<bf16x4*>(&Vs[SL_][c_][voff[3]]) =                         \
          __builtin_shufflevector(pv[c_][1], pv[c_][1], 4, 5, 6, 7);              \
    }                                                                             \
  } while (0)

  LOAD_PAIR_(0);
  WRITE_PAIR_(0);
  __syncthreads();

  for (int p = 0; p < npairs; ++p) {
    const int slot = p & 1;
    const bool more = (p + 1 < npairs);
    if (more) LOAD_PAIR_(p + 1);  // lands under this pair's compute
#pragma unroll
    for (int c = 0; c < 2; ++c) {
      const int kv = p * 128 + c * 64;
      const bf16_t* Kb = Ks[slot][c];
      const bf16_t* Vb = Vs[slot][c];
      // K fragments: read once, shared by both subtiles
      bf16x8 kf0[4], kf1[4];
#pragma unroll
      for (int n = 0; n < 4; ++n) {
        kf0[n] = *reinterpret_cast<const bf16x8*>(Kb + frow + n * 1024 + fx0);
        kf1[n] = *reinterpret_cast<const bf16x8*>(Kb + frow + n * 1024 + fx1);
      }
      f32x4 sa[2][4];
#pragma unroll
      for (int s = 0; s < 2; ++s) {
        if (kv > sub0 + s * 16 + 15) continue;
#pragma unroll
        for (int n = 0; n < 4; ++n) {
          f32x4 z = {};
          z = MFMA_16x16x32(kf0[n], qf[s][0], z);
          z = MFMA_16x16x32(kf1[n], qf[s][1], z);
          sa[s][n] = z;
        }
      }
      bf16x8 pb[2][2];
#pragma unroll
      for (int s = 0; s < 2; ++s) {
        const int subrow = sub0 + s * 16;
        if (kv > subrow + 15) continue;
        if (kv + 63 > subrow) {
          const int qrow = subrow + lr;
          const int kbase = kv + lk * 4;
#pragma unroll
          for (int n = 0; n < 4; ++n)
#pragma unroll
            for (int r = 0; r < 4; ++r)
              if (kbase + n * 16 + r > qrow) sa[s][n][r] = -INFINITY;
        }
        float mx = fmaxf(fmaxf(fmaxf(sa[s][0][0], sa[s][0][1]), fmaxf(sa[s][0][2], sa[s][0][3])),
                         fmaxf(fmaxf(sa[s][1][0], sa[s][1][1]), fmaxf(sa[s][1][2], sa[s][1][3])));
        mx = fmaxf(mx, fmaxf(fmaxf(fmaxf(sa[s][2][0], sa[s][2][1]), fmaxf(sa[s][2][2], sa[s][2][3])),
                             fmaxf(fmaxf(sa[s][3][0], sa[s][3][1]), fmaxf(sa[s][3][2], sa[s][3][3]))));
        mx = fmaxf(mx, __shfl_xor(mx, 16));
        mx = fmaxf(mx, __shfl_xor(mx, 32));
        if (!__all(mx <= mrow[s] + 8.0f)) {  // defer-max (T13)
          const float mnew = fmaxf(mrow[s], mx);
          const float scl = fast_exp2(mrow[s] - mnew);
          mrow[s] = mnew;
#pragma unroll
          for (int r = 0; r < 4; ++r) lacc[s][r] *= scl;
#pragma unroll
          for (int n = 0; n < 4; ++n)
#pragma unroll
            for (int r = 0; r < 4; ++r) o[s][n][r] *= scl;
        }
#pragma unroll
        for (int n = 0; n < 4; ++n)
#pragma unroll
          for (int r = 0; r < 4; ++r) sa[s][n][r] = fast_exp2(sa[s][n][r] - mrow[s]);
#pragma unroll
        for (int r = 0; r < 4; ++r) {
          pb[s][0][r] = (bf16_t)sa[s][0][r];
          pb[s][0][4 + r] = (bf16_t)sa[s][1][r];
          pb[s][1][r] = (bf16_t)sa[s][2][r];
          pb[s][1][4 + r] = (bf16_t)sa[s][3][r];
        }
        // denominator via matrix pipe (k-reduce crosses lanes)
        lacc[s] = MFMA_16x16x32(ones, pb[s][0], lacc[s]);
        lacc[s] = MFMA_16x16x32(ones, pb[s][1], lacc[s]);
      }
      // V fragments: read once, shared by both subtiles
      bf16x8 vf0[4], vf1[4];
#pragma unroll
      for (int n = 0; n < 4; ++n) {
        vf0[n] = *reinterpret_cast<const bf16x8*>(Vb + frow + n * 1024 + fx0);
        vf1[n] = *reinterpret_cast<const bf16x8*>(Vb + frow + n * 1024 + fx1);
      }
#pragma unroll
      for (int s = 0; s < 2; ++s) {
        if (kv > sub0 + s * 16 + 15) continue;
#pragma unroll
        for (int n = 0; n < 4; ++n) {
          o[s][n] = MFMA_16x16x32(vf0[n], pb[s][0], o[s][n]);
          o[s][n] = MFMA_16x16x32(vf1[n], pb[s][1], o[s][n]);
        }
      }
    }
    if (more) {
      WRITE_PAIR_(slot ^ 1);  // implicit vmcnt wait on pk/pv uses
      __syncthreads();
    }
  }
#undef LOAD_PAIR_
#undef WRITE_PAIR_

  const int b_ = bh >> 4, h_ = bh & 15;
#pragma unroll
  for (int s = 0; s < 2; ++s) {
    const float inv = 1.0f / lacc[s][0];  // all 4 elements equal; full k-sum
    const int qrow = sub0 + s * 16 + lr;
    bf16_t* op = aout + ((size_t)b_ * Ssz + qrow) * Dsz + h_ * DKd + lk * 4;
#pragma unroll
    for (int n = 0; n < 4; ++n) {
      const bf16x4 ov = {(bf16_t)(o[s][n][0] * inv), (bf16_t)(o[s][n][1] * inv),
                         (bf16_t)(o[s][n][2] * inv), (bf16_t)(o[s][n][3] * inv)};
      *reinterpret_cast<bf16x4*>(op + n * 16) = ov;
    }
  }
}

extern "C" void kernel_launch(void* const* d_in, const int* in_sizes, int n_in,
                              void* d_out, int out_size, void* d_ws, size_t ws_size,
                              hipStream_t stream) {
  const float* x = (const float*)d_in[0];
  const int* pos = (const int*)d_in[1];
  const float* wqkv = (const float*)d_in[2];
  const float* wo = (const float*)d_in[3];
  float* out = (float*)d_out;

  bf16_t* xb = (bf16_t*)d_ws;
  bf16_t* wqkvb = xb + (size_t)Mrows * KD;
  bf16_t* wob = wqkvb + (size_t)N1 * KD;
  bf16_t* qbuf = wob + (size_t)Dsz * KD;
  bf16_t* kbuf = qbuf + (size_t)64 * Ssz * DKd;
  bf16_t* vtb = kbuf + (size_t)64 * Ssz * DKd;
  float2* tab = (float2*)(vtb + (size_t)64 * Ssz * DKd);
  bf16_t* aout = xb;

  {
    constexpr int total = Mrows * KD / 4 + N1 * KD / 4 + Dsz * KD / 4 + Ssz * 32;
    prep_kernel<<<(total + 255) / 256, 256, 0, stream>>>(x, wqkv, wo, pos, xb, wqkvb, wob, tab);
  }

  gemm256_qkv_kernel<<<dim3(N1 / 192, Mrows / 256), 512, 0, stream>>>(
      xb, wqkvb, qbuf, kbuf, vtb, tab);

  attn_kernel<<<dim3(16 * 64), 256, 0, stream>>>(qbuf, kbuf, vtb, aout);

  gemm_out_kernel<<<dim3(Dsz / 128, Mrows / 256), 512, 0, stream>>>(
      aout, wob, out);
}

// Round 15
// 177.584 us; speedup vs baseline: 1.2399x; 1.2399x over previous
//
#include <hip/hip_runtime.h>
#include <hip/hip_bf16.h>
#include <math.h>

typedef __bf16 bf16_t;
typedef __attribute__((ext_vector_type(8))) __bf16 bf16x8;
typedef __attribute__((ext_vector_type(4))) __bf16 bf16x4;
typedef __attribute__((ext_vector_type(4))) float f32x4;

#define MFMA_16x16x32(A_, B_, C_) __builtin_amdgcn_mfma_f32_16x16x32_bf16((A_), (B_), (C_), 0, 0, 0)

#define Bsz 4
#define Ssz 2048
#define Dsz 1024
#define Hh 16
#define DKd 64
#define Mrows (Bsz * Ssz)  /* 8192 */
#define N1 (3 * Dsz)       /* 3072 */
#define KD Dsz             /* 1024 */

// raw v_exp_f32 (1 instr; libm exp2f adds denorm-guard selects)
static __device__ __forceinline__ float fast_exp2(float x) {
  float r;
  asm("v_exp_f32 %0, %1" : "=v"(r) : "v"(x));
  return r;
}

// ---- fused prep: x/wqkv/wo f32->bf16 converts + RoPE table, one launch ----
__global__ void prep_kernel(const float* __restrict__ x, const float* __restrict__ wqkv,
                            const float* __restrict__ wo, const int* __restrict__ pos,
                            bf16_t* __restrict__ xb, bf16_t* __restrict__ wqkvb,
                            bf16_t* __restrict__ wob, float2* __restrict__ tab) {
  constexpr int N4X = Mrows * KD / 4;
  constexpr int N4W = N1 * KD / 4;
  constexpr int N4O = Dsz * KD / 4;
  constexpr int NRT = Ssz * 32;
  const int i = blockIdx.x * blockDim.x + threadIdx.x;
  if (i < N4X) {
    float4 v = reinterpret_cast<const float4*>(x)[i];
    bf16x4 o = {(bf16_t)v.x, (bf16_t)v.y, (bf16_t)v.z, (bf16_t)v.w};
    reinterpret_cast<bf16x4*>(xb)[i] = o;
  } else if (i < N4X + N4W) {
    const int j = i - N4X;
    float4 v = reinterpret_cast<const float4*>(wqkv)[j];
    bf16x4 o = {(bf16_t)v.x, (bf16_t)v.y, (bf16_t)v.z, (bf16_t)v.w};
    reinterpret_cast<bf16x4*>(wqkvb)[j] = o;
  } else if (i < N4X + N4W + N4O) {
    const int j = i - N4X - N4W;
    float4 v = reinterpret_cast<const float4*>(wo)[j];
    bf16x4 o = {(bf16_t)v.x, (bf16_t)v.y, (bf16_t)v.z, (bf16_t)v.w};
    reinterpret_cast<bf16x4*>(wob)[j] = o;
  } else if (i < N4X + N4W + N4O + NRT) {
    const int j = i - N4X - N4W - N4O;
    const int s = j >> 5, f = j & 31;
    float inv_freq = powf(10000.0f, -(float)(2 * f) / 64.0f);
    float a = (float)pos[s] * inv_freq;
    tab[j] = make_float2(cosf(a), sinf(a));
  }
}

// ============ QKV GEMM: 256(M) x 192(N), BK=64, 8 waves, 8-PHASE (R10) ======
__global__ __launch_bounds__(512, 1) void gemm256_qkv_kernel(
    const bf16_t* __restrict__ A, const bf16_t* __restrict__ Bt,
    bf16_t* __restrict__ qb, bf16_t* __restrict__ kb, bf16_t* __restrict__ vtb,
    const float2* __restrict__ tab) {
  constexpr int NT = KD / 64;  // 16
  __shared__ __align__(16) bf16_t As[2][256 * 64];
  __shared__ __align__(16) bf16_t Bs[2][192 * 64];
  const int t = threadIdx.x;
  const int w = t >> 6, l = t & 63;
  const int lr = l & 15, lk = l >> 4;
  const int rs = lr >> 1;             // read-side swizzle (0..7)
  const int wm = w >> 2, wn = w & 3;  // 2M x 4N waves
  const int m0 = blockIdx.y * 256, n0 = blockIdx.x * 192;

  const int gcol = ((t & 7) ^ ((t >> 4) & 7)) * 8;
  const bf16_t* gA = A + (size_t)(m0 + (t >> 3)) * KD + gcol;
  const bf16_t* gB = Bt + (size_t)(n0 + (t >> 3)) * KD + gcol;

  f32x4 acc[8][3] = {};
  bf16x8 bfv[3][2];

#define LDA_(I_, SB_, KT_)                                                        \
  __builtin_amdgcn_global_load_lds(gA + (size_t)(I_) * 64 * KD + (KT_),           \
                                   &As[SB_][((I_) * 64 + w * 8) * 64], 16, 0, 0)
#define LDB_(I_, SB_, KT_)                                                        \
  __builtin_amdgcn_global_load_lds(gB + (size_t)(I_) * 64 * KD + (KT_),           \
                                   &Bs[SB_][((I_) * 64 + w * 8) * 64], 16, 0, 0)

#define PH(BUF_, P_, STG0_, STG1_, VMW_)                                          \
  do {                                                                            \
    if ((P_) == 0) {                                                              \
      _Pragma("unroll") for (int n_ = 0; n_ < 3; ++n_) {                          \
        const int R_ = wn * 48 + n_ * 16 + lr;                                    \
        bfv[n_][0] = *reinterpret_cast<const bf16x8*>(                            \
            &Bs[BUF_][R_ * 64 + ((lk ^ rs) * 8)]);                                \
        bfv[n_][1] = *reinterpret_cast<const bf16x8*>(                            \
            &Bs[BUF_][R_ * 64 + (((4 + lk) ^ rs) * 8)]);                          \
      }                                                                           \
    }                                                                             \
    bf16x8 af0_[2], af1_[2];                                                      \
    {                                                                             \
      const int Ra_ = wm * 128 + (P_) * 32 + lr;                                  \
      const int Rb_ = Ra_ + 16;                                                   \
      af0_[0] = *reinterpret_cast<const bf16x8*>(&As[BUF_][Ra_ * 64 + ((lk ^ rs) * 8)]);       \
      af0_[1] = *reinterpret_cast<const bf16x8*>(&As[BUF_][Ra_ * 64 + (((4 + lk) ^ rs) * 8)]); \
      af1_[0] = *reinterpret_cast<const bf16x8*>(&As[BUF_][Rb_ * 64 + ((lk ^ rs) * 8)]);       \
      af1_[1] = *reinterpret_cast<const bf16x8*>(&As[BUF_][Rb_ * 64 + (((4 + lk) ^ rs) * 8)]); \
    }                                                                             \
    STG0_;                                                                        \
    STG1_;                                                                        \
    __builtin_amdgcn_s_barrier();                                                 \
    asm volatile("s_waitcnt lgkmcnt(0)" ::: "memory");                            \
    __builtin_amdgcn_sched_barrier(0);                                            \
    __builtin_amdgcn_s_setprio(1);                                                \
    _Pragma("unroll") for (int n_ = 0; n_ < 3; ++n_) {                            \
      acc[(P_)*2][n_] = MFMA_16x16x32(af0_[0], bfv[n_][0], acc[(P_)*2][n_]);      \
      acc[(P_)*2][n_] = MFMA_16x16x32(af0_[1], bfv[n_][1], acc[(P_)*2][n_]);      \
      acc[(P_)*2 + 1][n_] = MFMA_16x16x32(af1_[0], bfv[n_][0], acc[(P_)*2 + 1][n_]); \
      acc[(P_)*2 + 1][n_] = MFMA_16x16x32(af1_[1], bfv[n_][1], acc[(P_)*2 + 1][n_]); \
    }                                                                             \
    __builtin_amdgcn_s_setprio(0);                                                \
    VMW_;                                                                         \
    __builtin_amdgcn_s_barrier();                                                 \
  } while (0)

#define VM4_ do { asm volatile("s_waitcnt vmcnt(4)" ::: "memory"); __builtin_amdgcn_sched_barrier(0); } while (0)
#define VM2_ do { asm volatile("s_waitcnt vmcnt(2)" ::: "memory"); __builtin_amdgcn_sched_barrier(0); } while (0)

#define TILE_(BUF_, KTN_)                                                         \
  do {                                                                            \
    PH(BUF_, 0, LDB_(0, (BUF_) ^ 1, KTN_), LDB_(1, (BUF_) ^ 1, KTN_), (void)0);   \
    PH(BUF_, 1, LDB_(2, (BUF_) ^ 1, KTN_), LDA_(0, (BUF_) ^ 1, KTN_), VM4_);      \
    PH(BUF_, 2, LDA_(2, (BUF_) ^ 1, KTN_), LDA_(1, (BUF_) ^ 1, KTN_), (void)0);   \
    PH(BUF_, 3, LDA_(3, (BUF_) ^ 1, KTN_), (void)0, VM2_);                        \
  } while (0)

  LDB_(0, 0, 0); LDB_(1, 0, 0); LDB_(2, 0, 0);
  LDA_(0, 0, 0); LDA_(2, 0, 0); LDA_(1, 0, 0); LDA_(3, 0, 0);
  asm volatile("s_waitcnt vmcnt(2)" ::: "memory");
  __builtin_amdgcn_s_barrier();

#pragma unroll 1
  for (int tt = 0; tt < NT; tt += 2) {
    const int ktn0 = ((tt + 1) & (NT - 1)) * 64;  // last tile wraps to 0 (dead buf)
    TILE_(0, ktn0);
    const int ktn1 = ((tt + 2) & (NT - 1)) * 64;
    TILE_(1, ktn1);
  }
#undef TILE_
#undef VM4_
#undef VM2_
#undef PH
#undef LDA_
#undef LDB_

  // ---- epilogue: per-n section decode ----
#pragma unroll
  for (int n = 0; n < 3; ++n) {
    const int colbase = n0 + wn * 48 + n * 16;
    const int sect = colbase >> 10;  // 0=q 1=k 2=v
    const int h = (colbase >> 6) & 15;
    const int dk = (colbase & 63) + lr;
    if (sect < 2) {
      bf16_t* dst0 = (sect == 0) ? qb : kb;
#pragma unroll
      for (int m = 0; m < 8; ++m)
#pragma unroll
        for (int r = 0; r < 4; ++r) {
          const int grow = m0 + wm * 128 + m * 16 + lk * 4 + r;
          const int bb = grow >> 11, s = grow & (Ssz - 1);
          const float v = acc[m][n][r];
          const float pv = __shfl_xor(v, 1);
          const float2 cs = tab[(s << 5) | (dk >> 1)];
          float vr = (dk & 1) ? (pv * cs.y + v * cs.x) : (v * cs.x - pv * cs.y);
          if (sect == 0) vr *= 0.18033688f;  // (1/8) * log2(e): exp2 softmax
          dst0[((size_t)(bb * Hh + h) * Ssz + s) * DKd + dk] = (bf16_t)vr;
        }
    } else {
#pragma unroll
      for (int m = 0; m < 8; ++m) {
        const int grow0 = m0 + wm * 128 + m * 16 + lk * 4;
        const int bb = grow0 >> 11, s0 = grow0 & (Ssz - 1);
        const bf16x4 ov = {(bf16_t)acc[m][n][0], (bf16_t)acc[m][n][1],
                           (bf16_t)acc[m][n][2], (bf16_t)acc[m][n][3]};
        *reinterpret_cast<bf16x4*>(
            vtb + ((size_t)(bb * Hh + h) * DKd + dk) * Ssz + s0) = ov;
      }
    }
  }
}

// ============ out-proj GEMM: 256(M) x 128(N), BK=64, 8 waves, 8-PHASE =======
__global__ __launch_bounds__(512, 1) void gemm_out_kernel(
    const bf16_t* __restrict__ A, const bf16_t* __restrict__ Bt,
    float* __restrict__ fout) {
  constexpr int NT = KD / 64;  // 16
  __shared__ __align__(16) bf16_t As[2][256 * 64];
  __shared__ __align__(16) bf16_t Bs[2][128 * 64];
  const int t = threadIdx.x;
  const int w = t >> 6, l = t & 63;
  const int lr = l & 15, lk = l >> 4;
  const int rs = lr >> 1;
  const int wm = w >> 2, wn = w & 3;
  const int m0 = blockIdx.y * 256, n0 = blockIdx.x * 128;

  const int gcol = ((t & 7) ^ ((t >> 4) & 7)) * 8;
  const bf16_t* gA = A + (size_t)(m0 + (t >> 3)) * KD + gcol;
  const bf16_t* gB = Bt + (size_t)(n0 + (t >> 3)) * KD + gcol;

  f32x4 acc[8][2] = {};
  bf16x8 bfv[2][2];

#define OLDA_(I_, SB_, KT_)                                                       \
  __builtin_amdgcn_global_load_lds(gA + (size_t)(I_) * 64 * KD + (KT_),           \
                                   &As[SB_][((I_) * 64 + w * 8) * 64], 16, 0, 0)
#define OLDB_(I_, SB_, KT_)                                                       \
  __builtin_amdgcn_global_load_lds(gB + (size_t)(I_) * 64 * KD + (KT_),           \
                                   &Bs[SB_][((I_) * 64 + w * 8) * 64], 16, 0, 0)

#define OPH(BUF_, P_, STG0_, STG1_, VMW_)                                         \
  do {                                                                            \
    if ((P_) == 0) {                                                              \
      _Pragma("unroll") for (int n_ = 0; n_ < 2; ++n_) {                          \
        const int R_ = wn * 32 + n_ * 16 + lr;                                    \
        bfv[n_][0] = *reinterpret_cast<const bf16x8*>(                            \
            &Bs[BUF_][R_ * 64 + ((lk ^ rs) * 8)]);                                \
        bfv[n_][1] = *reinterpret_cast<const bf16x8*>(                            \
            &Bs[BUF_][R_ * 64 + (((4 + lk) ^ rs) * 8)]);                          \
      }                                                                           \
    }                                                                             \
    bf16x8 af0_[2], af1_[2];                                                      \
    {                                                                             \
      const int Ra_ = wm * 128 + (P_) * 32 + lr;                                  \
      const int Rb_ = Ra_ + 16;                                                   \
      af0_[0] = *reinterpret_cast<const bf16x8*>(&As[BUF_][Ra_ * 64 + ((lk ^ rs) * 8)]);       \
      af0_[1] = *reinterpret_cast<const bf16x8*>(&As[BUF_][Ra_ * 64 + (((4 + lk) ^ rs) * 8)]); \
      af1_[0] = *reinterpret_cast<const bf16x8*>(&As[BUF_][Rb_ * 64 + ((lk ^ rs) * 8)]);       \
      af1_[1] = *reinterpret_cast<const bf16x8*>(&As[BUF_][Rb_ * 64 + (((4 + lk) ^ rs) * 8)]); \
    }                                                                             \
    STG0_;                                                                        \
    STG1_;                                                                        \
    __builtin_amdgcn_s_barrier();                                                 \
    asm volatile("s_waitcnt lgkmcnt(0)" ::: "memory");                            \
    __builtin_amdgcn_sched_barrier(0);                                            \
    __builtin_amdgcn_s_setprio(1);                                                \
    _Pragma("unroll") for (int n_ = 0; n_ < 2; ++n_) {                            \
      acc[(P_)*2][n_] = MFMA_16x16x32(af0_[0], bfv[n_][0], acc[(P_)*2][n_]);      \
      acc[(P_)*2][n_] = MFMA_16x16x32(af0_[1], bfv[n_][1], acc[(P_)*2][n_]);      \
      acc[(P_)*2 + 1][n_] = MFMA_16x16x32(af1_[0], bfv[n_][0], acc[(P_)*2 + 1][n_]); \
      acc[(P_)*2 + 1][n_] = MFMA_16x16x32(af1_[1], bfv[n_][1], acc[(P_)*2 + 1][n_]); \
    }                                                                             \
    __builtin_amdgcn_s_setprio(0);                                                \
    VMW_;                                                                         \
    __builtin_amdgcn_s_barrier();                                                 \
  } while (0)

#define OVM4_ do { asm volatile("s_waitcnt vmcnt(4)" ::: "memory"); __builtin_amdgcn_sched_barrier(0); } while (0)
#define OVM2_ do { asm volatile("s_waitcnt vmcnt(2)" ::: "memory"); __builtin_amdgcn_sched_barrier(0); } while (0)

#define OTILE_(BUF_, KTN_)                                                        \
  do {                                                                            \
    OPH(BUF_, 0, OLDB_(0, (BUF_) ^ 1, KTN_), OLDB_(1, (BUF_) ^ 1, KTN_), (void)0);\
    OPH(BUF_, 1, OLDA_(0, (BUF_) ^ 1, KTN_), OLDA_(2, (BUF_) ^ 1, KTN_), OVM4_);  \
    OPH(BUF_, 2, OLDA_(1, (BUF_) ^ 1, KTN_), OLDA_(3, (BUF_) ^ 1, KTN_), (void)0);\
    OPH(BUF_, 3, (void)0, (void)0, OVM2_);                                        \
  } while (0)

  OLDB_(0, 0, 0); OLDB_(1, 0, 0);
  OLDA_(0, 0, 0); OLDA_(2, 0, 0); OLDA_(1, 0, 0); OLDA_(3, 0, 0);
  asm volatile("s_waitcnt vmcnt(2)" ::: "memory");
  __builtin_amdgcn_s_barrier();

#pragma unroll 1
  for (int tt = 0; tt < NT; tt += 2) {
    const int ktn0 = ((tt + 1) & (NT - 1)) * 64;
    OTILE_(0, ktn0);
    const int ktn1 = ((tt + 2) & (NT - 1)) * 64;
    OTILE_(1, ktn1);
  }
#undef OTILE_
#undef OVM4_
#undef OVM2_
#undef OPH
#undef OLDA_
#undef OLDB_

#pragma unroll
  for (int m = 0; m < 8; ++m)
#pragma unroll
    for (int r = 0; r < 4; ++r) {
      const int grow = m0 + wm * 128 + m * 16 + lk * 4 + r;
      float* op = fout + (size_t)grow * Dsz + n0 + wn * 32 + lr;
      op[0] = acc[m][0][r];
      op[16] = acc[m][1][r];
    }
}

// ---------------- causal flash attention (R13 best-known config) ----------
// 32 KB LDS dbuf, single barrier/KV-tile, hoisted K/V fragments, raw v_exp
// softmax + defer-max (T13). Occupancy ~2-3 blocks/CU does the MFMA/VALU
// anti-alignment across blocks (R14 showed trading occupancy for intra-block
// drift regresses 76 -> 122 us).
__global__ __launch_bounds__(256, 3) void attn_kernel(
    const bf16_t* __restrict__ qb, const bf16_t* __restrict__ kb,
    const bf16_t* __restrict__ vtb, bf16_t* __restrict__ aout) {
  __shared__ __align__(16) bf16_t Ks[2][64 * 64];
  __shared__ __align__(16) bf16_t Vs[2][64 * 64];
  const int t = threadIdx.x, w = t >> 6, l = t & 63;
  const int lr = l & 15, lk = l >> 4;
  const int bid = blockIdx.x;
  const int bh = (bid & 7) * 8 + ((bid >> 3) & 7);
  const int qt = 15 - (bid >> 6);  // heavy-first
  const int q0 = qt * 128;
  const int sub0 = q0 + w * 32;

  const bf16_t* qbase = qb + ((size_t)bh * Ssz + sub0) * DKd;
  bf16x8 qf[2][2];
#pragma unroll
  for (int s = 0; s < 2; ++s) {
    qf[s][0] = *reinterpret_cast<const bf16x8*>(qbase + (s * 16 + lr) * DKd + lk * 8);
    qf[s][1] = *reinterpret_cast<const bf16x8*>(qbase + (s * 16 + lr) * DKd + 32 + lk * 8);
  }

  f32x4 o[2][4] = {};
  float mrow[2] = {-INFINITY, -INFINITY};
  float lsum[2] = {0.f, 0.f};

  const int srow = t >> 2;
  const int scc = (t & 3) * 2;
  const bf16_t* kg = kb + ((size_t)bh * Ssz + srow) * DKd + scc * 8;
  const bf16_t* vg = vtb + ((size_t)bh * DKd + srow) * Ssz + scc * 8;
  const int koff0 = srow * 64 + ((scc ^ (srow & 7)) * 8);
  const int koff1 = srow * 64 + (((scc + 1) ^ (srow & 7)) * 8);
  int voff[4];
#pragma unroll
  for (int u = 0; u < 2; ++u) {
    const int c = scc + u;
    const int B = 32 * (c >> 2) + 16 * (c & 1) + 4 * ((c & 3) >> 1);
    const int ch = B >> 3, off = B & 7;
    voff[2 * u] = srow * 64 + ((ch ^ (srow & 7)) * 8) + off;
    voff[2 * u + 1] = srow * 64 + (((ch + 1) ^ (srow & 7)) * 8) + off;
  }

  const int fx0 = (lk ^ (lr & 7)) * 8;
  const int fx1 = ((lk + 4) ^ (lr & 7)) * 8;
  const int frow = lr * 64;

  const int kvend = q0 + 128;
  bf16x8 pk0 = *reinterpret_cast<const bf16x8*>(kg);
  bf16x8 pk1 = *reinterpret_cast<const bf16x8*>(kg + 8);
  bf16x8 pv0 = *reinterpret_cast<const bf16x8*>(vg);
  bf16x8 pv1 = *reinterpret_cast<const bf16x8*>(vg + 8);

  *reinterpret_cast<bf16x8*>(&Ks[0][koff0]) = pk0;
  *reinterpret_cast<bf16x8*>(&Ks[0][koff1]) = pk1;
  *reinterpret_cast<bf16x4*>(&Vs[0][voff[0]]) = __builtin_shufflevector(pv0, pv0, 0, 1, 2, 3);
  *reinterpret_cast<bf16x4*>(&Vs[0][voff[1]]) = __builtin_shufflevector(pv0, pv0, 4, 5, 6, 7);
  *reinterpret_cast<bf16x4*>(&Vs[0][voff[2]]) = __builtin_shufflevector(pv1, pv1, 0, 1, 2, 3);
  *reinterpret_cast<bf16x4*>(&Vs[0][voff[3]]) = __builtin_shufflevector(pv1, pv1, 4, 5, 6, 7);
  __syncthreads();

  for (int kv = 0; kv < kvend; kv += 64) {
    const int buf = (kv >> 6) & 1;
    const bool more = (kv + 64 < kvend);
    if (more) {
      pk0 = *reinterpret_cast<const bf16x8*>(kg + (size_t)(kv + 64) * DKd);
      pk1 = *reinterpret_cast<const bf16x8*>(kg + (size_t)(kv + 64) * DKd + 8);
      pv0 = *reinterpret_cast<const bf16x8*>(vg + kv + 64);
      pv1 = *reinterpret_cast<const bf16x8*>(vg + kv + 64 + 8);
    }
    const bf16_t* Kb = Ks[buf];
    const bf16_t* Vb = Vs[buf];
    bf16x8 kf0[4], kf1[4];
#pragma unroll
    for (int n = 0; n < 4; ++n) {
      kf0[n] = *reinterpret_cast<const bf16x8*>(Kb + frow + n * 1024 + fx0);
      kf1[n] = *reinterpret_cast<const bf16x8*>(Kb + frow + n * 1024 + fx1);
    }
    f32x4 sa[2][4];
#pragma unroll
    for (int s = 0; s < 2; ++s) {
      if (kv > sub0 + s * 16 + 15) continue;
#pragma unroll
      for (int n = 0; n < 4; ++n) {
        f32x4 z = {};
        z = MFMA_16x16x32(kf0[n], qf[s][0], z);
        z = MFMA_16x16x32(kf1[n], qf[s][1], z);
        sa[s][n] = z;
      }
    }
    bf16x8 pb[2][2];
#pragma unroll
    for (int s = 0; s < 2; ++s) {
      const int subrow = sub0 + s * 16;
      if (kv > subrow + 15) continue;
      if (kv + 63 > subrow) {
        const int qrow = subrow + lr;
        const int kbase = kv + lk * 4;
#pragma unroll
        for (int n = 0; n < 4; ++n)
#pragma unroll
          for (int r = 0; r < 4; ++r)
            if (kbase + n * 16 + r > qrow) sa[s][n][r] = -INFINITY;
      }
      float mx = fmaxf(fmaxf(fmaxf(sa[s][0][0], sa[s][0][1]), fmaxf(sa[s][0][2], sa[s][0][3])),
                       fmaxf(fmaxf(sa[s][1][0], sa[s][1][1]), fmaxf(sa[s][1][2], sa[s][1][3])));
      mx = fmaxf(mx, fmaxf(fmaxf(fmaxf(sa[s][2][0], sa[s][2][1]), fmaxf(sa[s][2][2], sa[s][2][3])),
                           fmaxf(fmaxf(sa[s][3][0], sa[s][3][1]), fmaxf(sa[s][3][2], sa[s][3][3]))));
      mx = fmaxf(mx, __shfl_xor(mx, 16));
      mx = fmaxf(mx, __shfl_xor(mx, 32));
      if (!__all(mx <= mrow[s] + 8.0f)) {  // defer-max (T13)
        const float mnew = fmaxf(mrow[s], mx);
        const float scl = fast_exp2(mrow[s] - mnew);
        mrow[s] = mnew;
        lsum[s] *= scl;
#pragma unroll
        for (int n = 0; n < 4; ++n)
#pragma unroll
          for (int r = 0; r < 4; ++r) o[s][n][r] *= scl;
      }
      float ps = 0.f;
#pragma unroll
      for (int n = 0; n < 4; ++n)
#pragma unroll
        for (int r = 0; r < 4; ++r) {
          const float p = fast_exp2(sa[s][n][r] - mrow[s]);
          sa[s][n][r] = p;
          ps += p;
        }
      lsum[s] += ps;
#pragma unroll
      for (int r = 0; r < 4; ++r) {
        pb[s][0][r] = (bf16_t)sa[s][0][r];
        pb[s][0][4 + r] = (bf16_t)sa[s][1][r];
        pb[s][1][r] = (bf16_t)sa[s][2][r];
        pb[s][1][4 + r] = (bf16_t)sa[s][3][r];
      }
    }
    bf16x8 vf0[4], vf1[4];
#pragma unroll
    for (int n = 0; n < 4; ++n) {
      vf0[n] = *reinterpret_cast<const bf16x8*>(Vb + frow + n * 1024 + fx0);
      vf1[n] = *reinterpret_cast<const bf16x8*>(Vb + frow + n * 1024 + fx1);
    }
#pragma unroll
    for (int s = 0; s < 2; ++s) {
      if (kv > sub0 + s * 16 + 15) continue;
#pragma unroll
      for (int n = 0; n < 4; ++n) {
        o[s][n] = MFMA_16x16x32(vf0[n], pb[s][0], o[s][n]);
        o[s][n] = MFMA_16x16x32(vf1[n], pb[s][1], o[s][n]);
      }
    }
    if (more) {
      bf16_t* Kn = Ks[buf ^ 1];
      bf16_t* Vn = Vs[buf ^ 1];
      *reinterpret_cast<bf16x8*>(&Kn[koff0]) = pk0;
      *reinterpret_cast<bf16x8*>(&Kn[koff1]) = pk1;
      *reinterpret_cast<bf16x4*>(&Vn[voff[0]]) = __builtin_shufflevector(pv0, pv0, 0, 1, 2, 3);
      *reinterpret_cast<bf16x4*>(&Vn[voff[1]]) = __builtin_shufflevector(pv0, pv0, 4, 5, 6, 7);
      *reinterpret_cast<bf16x4*>(&Vn[voff[2]]) = __builtin_shufflevector(pv1, pv1, 0, 1, 2, 3);
      *reinterpret_cast<bf16x4*>(&Vn[voff[3]]) = __builtin_shufflevector(pv1, pv1, 4, 5, 6, 7);
      __syncthreads();
    }
  }
  const int b_ = bh >> 4, h_ = bh & 15;
#pragma unroll
  for (int s = 0; s < 2; ++s) {
    float sm = lsum[s];
    sm += __shfl_xor(sm, 16);
    sm += __shfl_xor(sm, 32);
    const float inv = 1.0f / sm;
    const int qrow = sub0 + s * 16 + lr;
    bf16_t* op = aout + ((size_t)b_ * Ssz + qrow) * Dsz + h_ * DKd + lk * 4;
#pragma unroll
    for (int n = 0; n < 4; ++n) {
      const bf16x4 ov = {(bf16_t)(o[s][n][0] * inv), (bf16_t)(o[s][n][1] * inv),
                         (bf16_t)(o[s][n][2] * inv), (bf16_t)(o[s][n][3] * inv)};
      *reinterpret_cast<bf16x4*>(op + n * 16) = ov;
    }
  }
}

extern "C" void kernel_launch(void* const* d_in, const int* in_sizes, int n_in,
                              void* d_out, int out_size, void* d_ws, size_t ws_size,
                              hipStream_t stream) {
  const float* x = (const float*)d_in[0];
  const int* pos = (const int*)d_in[1];
  const float* wqkv = (const float*)d_in[2];
  const float* wo = (const float*)d_in[3];
  float* out = (float*)d_out;

  bf16_t* xb = (bf16_t*)d_ws;
  bf16_t* wqkvb = xb + (size_t)Mrows * KD;
  bf16_t* wob = wqkvb + (size_t)N1 * KD;
  bf16_t* qbuf = wob + (size_t)Dsz * KD;
  bf16_t* kbuf = qbuf + (size_t)64 * Ssz * DKd;
  bf16_t* vtb = kbuf + (size_t)64 * Ssz * DKd;
  float2* tab = (float2*)(vtb + (size_t)64 * Ssz * DKd);
  bf16_t* aout = xb;

  {
    constexpr int total = Mrows * KD / 4 + N1 * KD / 4 + Dsz * KD / 4 + Ssz * 32;
    prep_kernel<<<(total + 255) / 256, 256, 0, stream>>>(x, wqkv, wo, pos, xb, wqkvb, wob, tab);
  }

  gemm256_qkv_kernel<<<dim3(N1 / 192, Mrows / 256), 512, 0, stream>>>(
      xb, wqkvb, qbuf, kbuf, vtb, tab);

  attn_kernel<<<dim3(16 * 64), 256, 0, stream>>>(qbuf, kbuf, vtb, aout);

  gemm_out_kernel<<<dim3(Dsz / 128, Mrows / 256), 512, 0, stream>>>(
      aout, wob, out);
}